// Round 12
// baseline (335.983 us; speedup 1.0000x reference)
//
#include <hip/hip_runtime.h>
#include <stdint.h>

typedef __attribute__((ext_vector_type(8))) short bf16x8;
typedef __attribute__((ext_vector_type(4))) float f32x4;
typedef __attribute__((ext_vector_type(4))) int i32x4;

// ---------------- threefry2x32 (exact JAX) ----------------
__host__ __device__ __forceinline__ uint32_t rotl32(uint32_t x, int d){
  return (x << d) | (x >> (32 - d));
}

__host__ __device__ __forceinline__ void threefry2x32(uint32_t k0, uint32_t k1,
                                                      uint32_t x0, uint32_t x1,
                                                      uint32_t* o0, uint32_t* o1){
  uint32_t ks2 = k0 ^ k1 ^ 0x1BD11BDAu;
  x0 += k0; x1 += k1;
  x0 += x1; x1 = rotl32(x1,13); x1 ^= x0;
  x0 += x1; x1 = rotl32(x1,15); x1 ^= x0;
  x0 += x1; x1 = rotl32(x1,26); x1 ^= x0;
  x0 += x1; x1 = rotl32(x1, 6); x1 ^= x0;
  x0 += k1; x1 += ks2 + 1u;
  x0 += x1; x1 = rotl32(x1,17); x1 ^= x0;
  x0 += x1; x1 = rotl32(x1,29); x1 ^= x0;
  x0 += x1; x1 = rotl32(x1,16); x1 ^= x0;
  x0 += x1; x1 = rotl32(x1,24); x1 ^= x0;
  x0 += ks2; x1 += k0 + 2u;
  x0 += x1; x1 = rotl32(x1,13); x1 ^= x0;
  x0 += x1; x1 = rotl32(x1,15); x1 ^= x0;
  x0 += x1; x1 = rotl32(x1,26); x1 ^= x0;
  x0 += x1; x1 = rotl32(x1, 6); x1 ^= x0;
  x0 += k0; x1 += k1 + 3u;
  x0 += x1; x1 = rotl32(x1,17); x1 ^= x0;
  x0 += x1; x1 = rotl32(x1,29); x1 ^= x0;
  x0 += x1; x1 = rotl32(x1,16); x1 ^= x0;
  x0 += x1; x1 = rotl32(x1,24); x1 ^= x0;
  x0 += k1; x1 += ks2 + 4u;
  x0 += x1; x1 = rotl32(x1,13); x1 ^= x0;
  x0 += x1; x1 = rotl32(x1,15); x1 ^= x0;
  x0 += x1; x1 = rotl32(x1,26); x1 ^= x0;
  x0 += x1; x1 = rotl32(x1, 6); x1 ^= x0;
  x0 += ks2; x1 += k0 + 5u;
  *o0 = x0; *o1 = x1;
}

// drop iff MSB(o0^o1) set (uniform<0.5 under partitionable bit-gen)
__device__ __forceinline__ uint32_t tf_dropbit(uint32_t k0, uint32_t k1, uint32_t j){
  uint32_t o0, o1;
  threefry2x32(k0, k1, 0u, j, &o0, &o1);
  return (o0 ^ o1) >> 31;
}

// single-instruction rotate: v_alignbit_b32 x,x,(32-d) == rotl(x,d)
__device__ __forceinline__ uint32_t rotl1(uint32_t x, int d){
  return __builtin_amdgcn_alignbit(x, x, (uint32_t)(32 - d));
}

// ---------------- bf16 helpers ----------------
__device__ __forceinline__ ushort f2bf(float f){
  uint32_t u = __float_as_uint(f);
  u += 0x7FFFu + ((u >> 16) & 1u);   // rne
  return (ushort)(u >> 16);
}
__device__ __forceinline__ float bf2f(ushort b){
  return __uint_as_float(((uint32_t)b) << 16);
}
// packed f32x2 -> bf16x2 (RNE), single instruction
__device__ __forceinline__ uint32_t cvt_pk_bf16(float lo, float hi){
  uint32_t r;
  asm("v_cvt_pk_bf16_f32 %0, %1, %2" : "=v"(r) : "v"(lo), "v"(hi));
  return r;
}

// 4 elements j..j+3: 4 threefry chains hand-interleaved; value-pack via
// v_cvt_pk_bf16_f32; drop via sign-mask + v_perm. {dword(e0,e1), dword(e2,e3)}.
__device__ __forceinline__ uint2 drop4(uint32_t k0, uint32_t k1, uint32_t j,
                                       float f0, float f1, float f2, float f3){
  uint32_t ks2 = k0 ^ k1 ^ 0x1BD11BDAu;
  uint32_t xa0 = k0, xa1 = (j + 0u) + k1;
  uint32_t xb0 = k0, xb1 = (j + 1u) + k1;
  uint32_t xc0 = k0, xc1 = (j + 2u) + k1;
  uint32_t xd0 = k0, xd1 = (j + 3u) + k1;
#define RR(d)                                              \
  xa0 += xa1; xa1 = rotl1(xa1, d); xa1 ^= xa0;             \
  xb0 += xb1; xb1 = rotl1(xb1, d); xb1 ^= xb0;             \
  xc0 += xc1; xc1 = rotl1(xc1, d); xc1 ^= xc0;             \
  xd0 += xd1; xd1 = rotl1(xd1, d); xd1 ^= xd0;
#define INJ(ka, kb)                                        \
  { uint32_t A = (ka), B = (kb);                           \
    xa0 += A; xa1 += B; xb0 += A; xb1 += B;                \
    xc0 += A; xc1 += B; xd0 += A; xd1 += B; }
  RR(13) RR(15) RR(26) RR(6)  INJ(k1, ks2 + 1u)
  RR(17) RR(29) RR(16) RR(24) INJ(ks2, k0 + 2u)
  RR(13) RR(15) RR(26) RR(6)  INJ(k0, k1 + 3u)
  RR(17) RR(29) RR(16) RR(24) INJ(k1, ks2 + 4u)
  RR(13) RR(15) RR(26) RR(6)  INJ(ks2, k0 + 5u)
#undef RR
#undef INJ
  uint32_t ba = xa0 ^ xa1, bb = xb0 ^ xb1, bc = xc0 ^ xc1, bd = xd0 ^ xd1;
  uint32_t sa = (uint32_t)((int32_t)ba >> 31);   // all-ones if drop
  uint32_t sb = (uint32_t)((int32_t)bb >> 31);
  uint32_t sc = (uint32_t)((int32_t)bc >> 31);
  uint32_t sd = (uint32_t)((int32_t)bd >> 31);
  uint32_t v01 = cvt_pk_bf16(f0, f1);
  uint32_t v23 = cvt_pk_bf16(f2, f3);
  uint32_t m01 = __builtin_amdgcn_perm(sb, sa, 0x07060302u);
  uint32_t m23 = __builtin_amdgcn_perm(sd, sc, 0x07060302u);
  return make_uint2(v01 & ~m01, v23 & ~m23);
}

// ---------------- K0: pack 2*W1 fragments + ck precompute (one block) --------
__global__ void k_prep(const float* __restrict__ W1, ushort* __restrict__ w1p,
                       const float* __restrict__ PI, const float* __restrict__ PREs,
                       float* __restrict__ ckg){
  int t = threadIdx.x;
  for (int u = 0; u < 32; ++u){
    int idx = u * 256 + t;            // = k*16 + c
    int k = idx >> 4, c = idx & 15;
    w1p[((k >> 3) * 16 + c) * 8 + (k & 7)] = f2bf(2.0f * W1[idx]);
  }
  if (t < 16){
    float s = logf(PI[t]);
    #pragma unroll
    for (int j = 0; j < 16; ++j) s += 0.5f * logf(PREs[t * 16 + j]);
    ckg[t] = s - 8.0f * logf(6.28318530717958647692f);
  }
}

// ---------------- K1: fused {rp scatter} + {support1 = dropout(x) @ W1} ------
// K-split x8: block = 512 threads = 8 waves, all 8 K-octants of one 16-row
// tile (2 MFMA steps each) -> 50000 gemm waves = 48.8/SIMD (six full
// 8-resident passes, ~2% tail). rp scatter blocks interleaved 1:1.
__global__ __launch_bounds__(512, 8) void k_main(
    const float* __restrict__ x, const ushort* __restrict__ w1p,
    ushort* __restrict__ s1, const int* __restrict__ rowv, int* __restrict__ rp,
    uint32_t dk0, uint32_t dk1, int N, int E, int nbG, int nbR){
  __shared__ float part[8][16][17];   // 8.7KB
  int bid = blockIdx.x;
  if (!(bid & 1)){
    // ---- rp scatter block ----
    int rb = bid >> 1;
    if (rb < nbR){
      int e = rb * 512 + threadIdx.x;
      if (e <= E){
        int r0 = (e > 0) ? rowv[e - 1] : -1;
        int r1 = (e < E) ? rowv[e] : N;
        for (int r = r0 + 1; r <= r1; ++r) rp[r] = e;
      }
    }
    return;
  }
  int gb = bid >> 1;
  if (gb >= nbG) return;

  int t = threadIdx.x;
  int l = t & 63, p = t >> 6;            // p = K-octant (0..7)
  int rA = l & 15, kg = l >> 4;
  int r0 = gb * 16;
  int rr = r0 + rA; if (rr > N - 1) rr = N - 1;
  const float4* xv = reinterpret_cast<const float4*>(
      x + (size_t)rr * 512 + (p * 64 + kg * 8));
  uint32_t jb = (uint32_t)rr * 512u + (uint32_t)(p * 64 + kg * 8);

  const bf16x8* bp = reinterpret_cast<const bf16x8*>(w1p);
  bf16x8 B0 = bp[((p * 2 + 0) * 4 + kg) * 16 + rA];
  bf16x8 B1 = bp[((p * 2 + 1) * 4 + kg) * 16 + rA];
  float4 xa = xv[0], xb = xv[1];
  float4 xc = xv[8], xd = xv[9];
  __builtin_amdgcn_sched_barrier(0);   // all loads issued before the hash burn

  f32x4 acc = {0.f, 0.f, 0.f, 0.f};
  {
    uint2 lo = drop4(dk0, dk1, jb,      xa.x, xa.y, xa.z, xa.w);
    uint2 hi = drop4(dk0, dk1, jb + 4u, xb.x, xb.y, xb.z, xb.w);
    i32x4 ai = {(int)lo.x, (int)lo.y, (int)hi.x, (int)hi.y};
    acc = __builtin_amdgcn_mfma_f32_16x16x32_bf16(
        __builtin_bit_cast(bf16x8, ai), B0, acc, 0, 0, 0);
  }
  {
    uint2 lo = drop4(dk0, dk1, jb + 32u, xc.x, xc.y, xc.z, xc.w);
    uint2 hi = drop4(dk0, dk1, jb + 36u, xd.x, xd.y, xd.z, xd.w);
    i32x4 ai = {(int)lo.x, (int)lo.y, (int)hi.x, (int)hi.y};
    acc = __builtin_amdgcn_mfma_f32_16x16x32_bf16(
        __builtin_bit_cast(bf16x8, ai), B1, acc, 0, 0, 0);
  }

  // C/D: col = lane&15, row = (lane>>4)*4 + reg -> stash partials per octant
  #pragma unroll
  for (int i2 = 0; i2 < 4; ++i2) part[p][kg * 4 + i2][rA] = acc[i2];
  __syncthreads();
  if (t < 256){
    int row = t >> 4, col = t & 15;
    int n = r0 + row;
    float sum = ((part[0][row][col] + part[1][row][col])
               + (part[2][row][col] + part[3][row][col]))
              + ((part[4][row][col] + part[5][row][col])
               + (part[6][row][col] + part[7][row][col]));
    if (n < N) s1[(size_t)n * 16 + col] = f2bf(sum);
  }
}

// ---------------- K2: h = spmm(s1); GMM-probs, relu, dropout2, @W2 -> s2(bf16) --
// ONE ROW PER WAVE: lane = d + 16*esub; 4 esub groups split the row's edges
// (serial chain 32 -> 8 edges/lane, 2 accumulators). Row bounds wave-uniform.
__global__ __launch_bounds__(256) void k_spmm1(
    const float* __restrict__ adj, const int* __restrict__ colv,
    const int* __restrict__ rp, const ushort* __restrict__ s1,
    const float* __restrict__ MUs, const float* __restrict__ PREs,
    const float* __restrict__ W2, const float* __restrict__ ckg,
    ushort* __restrict__ s2, float* __restrict__ partials,
    uint32_t dk0, uint32_t dk1, int N){
  __shared__ float muT[256], preT[256], w2s[256], ck[16];
  __shared__ float bsum;
  int t = threadIdx.x;
  {
    int j = t >> 4, k = t & 15;     // transposed: muT[j*16+k] = MUs[k][j]
    muT[t]  = MUs[k * 16 + j];
    preT[t] = PREs[k * 16 + j];
  }
  w2s[t] = W2[t];
  if (t < 16) ck[t] = ckg[t];
  if (t == 0) bsum = 0.f;
  __syncthreads();

  int l = t & 63, w = t >> 6;
  int d = l & 15, esub = l >> 4;
  int i = blockIdx.x * 4 + w;
  float h = 0.f;
  if (i < N){
    int e0 = rp[i], e1 = rp[i + 1];
    const ushort* s1d = s1 + d;
    float ha = 0.f, hb = 0.f;
    int e = e0 + esub;
    for (; e + 4 < e1; e += 8){
      ha += adj[e]     * bf2f(s1d[(size_t)colv[e]     * 16]);
      hb += adj[e + 4] * bf2f(s1d[(size_t)colv[e + 4] * 16]);
    }
    if (e < e1) ha += adj[e] * bf2f(s1d[(size_t)colv[e] * 16]);
    h = ha + hb;
  }
  h += __shfl_xor(h, 16, 64);
  h += __shfl_xor(h, 32, 64);   // h(d) replicated across the 4 esub groups

  // GMM log-likelihood: lane's component k = d, iterate dims j
  float lc = ck[d];
  #pragma unroll
  for (int j = 0; j < 16; ++j){
    float hj = __shfl(h, j, 16);
    float df = hj - muT[j * 16 + d];
    lc -= 0.5f * df * df * preT[j * 16 + d];
  }
  float m = lc;
  #pragma unroll
  for (int s = 1; s < 16; s <<= 1) m = fmaxf(m, __shfl_xor(m, s, 16));
  if (l == 0 && i < N) atomicAdd(&bsum, m);

  // relu -> dropout(dk2) -> @W2 (esub groups compute identically)
  float v = fmaxf(h, 0.f);
  float xd2 = (i < N && !tf_dropbit(dk0, dk1, (uint32_t)i * 16u + (uint32_t)d))
              ? 2.0f * v : 0.f;
  float s2v = 0.f;
  #pragma unroll
  for (int j = 0; j < 16; ++j)
    s2v += __shfl(xd2, j, 16) * w2s[j * 16 + d];
  if (i < N && l < 16) s2[(size_t)i * 16 + d] = f2bf(s2v);
  __syncthreads();
  if (t == 0) partials[blockIdx.x] = bsum;
}

// ---------------- K3: h2 = spmm(s2); log_softmax; block0 reduces partials ----
__global__ __launch_bounds__(256) void k_spmm2(
    const float* __restrict__ adj, const int* __restrict__ colv,
    const int* __restrict__ rp, const ushort* __restrict__ s2,
    const float* __restrict__ partials, int nparts,
    float* __restrict__ out, int N){
  int t = threadIdx.x;
  int l = t & 63, w = t >> 6;
  int d = l & 15, esub = l >> 4;
  int i = blockIdx.x * 4 + w;
  float h = 0.f;
  if (i < N){
    int e0 = rp[i], e1 = rp[i + 1];
    const ushort* s2d = s2 + d;
    float ha = 0.f, hb = 0.f;
    int e = e0 + esub;
    for (; e + 4 < e1; e += 8){
      ha += adj[e]     * bf2f(s2d[(size_t)colv[e]     * 16]);
      hb += adj[e + 4] * bf2f(s2d[(size_t)colv[e + 4] * 16]);
    }
    if (e < e1) ha += adj[e] * bf2f(s2d[(size_t)colv[e] * 16]);
    h = ha + hb;
  }
  h += __shfl_xor(h, 16, 64);
  h += __shfl_xor(h, 32, 64);
  float m = h;
  #pragma unroll
  for (int s = 1; s < 16; s <<= 1) m = fmaxf(m, __shfl_xor(m, s, 16));
  float ex = expf(h - m);
  float ssum = ex;
  #pragma unroll
  for (int s = 1; s < 16; s <<= 1) ssum += __shfl_xor(ssum, s, 16);
  if (i < N && l < 16) out[(size_t)i * 16 + d] = (h - m) - logf(ssum);

  if (blockIdx.x == 0){
    __shared__ float wsum[4];
    float s = 0.f;
    for (int q = t; q < nparts; q += 256) s += partials[q];
    #pragma unroll
    for (int sh = 1; sh < 64; sh <<= 1) s += __shfl_xor(s, sh, 64);
    if ((t & 63) == 0) wsum[t >> 6] = s;
    __syncthreads();
    if (t == 0)
      out[(size_t)N * 16] = -(wsum[0] + wsum[1] + wsum[2] + wsum[3]) / (float)N;
  }
}

extern "C" void kernel_launch(void* const* d_in, const int* in_sizes, int n_in,
                              void* d_out, int out_size, void* d_ws, size_t ws_size,
                              hipStream_t stream){
  const float* x    = (const float*)d_in[0];
  const float* W1   = (const float*)d_in[1];
  const float* W2   = (const float*)d_in[2];
  const float* adj  = (const float*)d_in[3];
  const float* PI   = (const float*)d_in[4];
  const float* MUs  = (const float*)d_in[5];
  const float* PREs = (const float*)d_in[6];
  const int*   rowv = (const int*)d_in[7];
  const int*   colv = (const int*)d_in[8];
  const int N = in_sizes[0] / 512;   // 100000
  const int E = in_sizes[3];         // 3200000
  float* out = (float*)d_out;

  // workspace layout
  char* ws = (char*)d_ws;
  float* ckg = (float*)ws;                                    // 16 floats
  int*   rp  = (int*)(ws + 256);                              // N+1 ints
  size_t rpBytes = (((size_t)(N + 1) * 4) + 255) & ~(size_t)255;
  ushort* s1 = (ushort*)(ws + 256 + rpBytes);                 // N*16 bf16
  size_t s1Bytes = (((size_t)N * 16 * 2) + 255) & ~(size_t)255;
  ushort* s2 = (ushort*)(ws + 256 + rpBytes + s1Bytes);       // N*16 bf16
  size_t s2Bytes = s1Bytes;
  float* partials = (float*)(ws + 256 + rpBytes + s1Bytes + s2Bytes);
  size_t pBytes = ((((size_t)N / 4 + 1) * 4) + 255) & ~(size_t)255;  // 25001 floats
  ushort* w1p = (ushort*)(ws + 256 + rpBytes + s1Bytes + s2Bytes + pBytes); // 16KB

  // dk1/dk2: fold-like split of key(42) = (0, 42)
  uint32_t d10, d11, d20, d21;
  threefry2x32(0u, 42u, 0u, 0u, &d10, &d11);  // dk1
  threefry2x32(0u, 42u, 0u, 1u, &d20, &d21);  // dk2

  k_prep<<<1, 256, 0, stream>>>(W1, w1p, PI, PREs, ckg);

  int nbG = N / 16;                            // 6250 gemm blocks (512 thr)
  int nbR = (E + 1 + 511) / 512;               // 6251 rp blocks (512 thr)
  int grid = 2 * ((nbG > nbR ? nbG : nbR)) + 2;
  k_main<<<grid, 512, 0, stream>>>(x, w1p, s1, rowv, rp, d10, d11, N, E, nbG, nbR);

  int nb2 = (N + 3) / 4;                       // 25000 blocks, 1 row/wave
  k_spmm1<<<nb2, 256, 0, stream>>>(adj, colv, rp, s1, MUs, PREs, W2, ckg,
                                   s2, partials, d20, d21, N);
  k_spmm2<<<nb2, 256, 0, stream>>>(adj, colv, rp, s2, partials, nb2, out, N);
}

// Round 13
// 195.724 us; speedup vs baseline: 1.7166x; 1.7166x over previous
//
#include <hip/hip_runtime.h>
#include <stdint.h>

typedef __attribute__((ext_vector_type(8))) short bf16x8;
typedef __attribute__((ext_vector_type(4))) float f32x4;
typedef __attribute__((ext_vector_type(4))) int i32x4;

// ---------------- threefry2x32 (exact JAX) ----------------
__host__ __device__ __forceinline__ uint32_t rotl32(uint32_t x, int d){
  return (x << d) | (x >> (32 - d));
}

__host__ __device__ __forceinline__ void threefry2x32(uint32_t k0, uint32_t k1,
                                                      uint32_t x0, uint32_t x1,
                                                      uint32_t* o0, uint32_t* o1){
  uint32_t ks2 = k0 ^ k1 ^ 0x1BD11BDAu;
  x0 += k0; x1 += k1;
  x0 += x1; x1 = rotl32(x1,13); x1 ^= x0;
  x0 += x1; x1 = rotl32(x1,15); x1 ^= x0;
  x0 += x1; x1 = rotl32(x1,26); x1 ^= x0;
  x0 += x1; x1 = rotl32(x1, 6); x1 ^= x0;
  x0 += k1; x1 += ks2 + 1u;
  x0 += x1; x1 = rotl32(x1,17); x1 ^= x0;
  x0 += x1; x1 = rotl32(x1,29); x1 ^= x0;
  x0 += x1; x1 = rotl32(x1,16); x1 ^= x0;
  x0 += x1; x1 = rotl32(x1,24); x1 ^= x0;
  x0 += ks2; x1 += k0 + 2u;
  x0 += x1; x1 = rotl32(x1,13); x1 ^= x0;
  x0 += x1; x1 = rotl32(x1,15); x1 ^= x0;
  x0 += x1; x1 = rotl32(x1,26); x1 ^= x0;
  x0 += x1; x1 = rotl32(x1, 6); x1 ^= x0;
  x0 += k0; x1 += k1 + 3u;
  x0 += x1; x1 = rotl32(x1,17); x1 ^= x0;
  x0 += x1; x1 = rotl32(x1,29); x1 ^= x0;
  x0 += x1; x1 = rotl32(x1,16); x1 ^= x0;
  x0 += x1; x1 = rotl32(x1,24); x1 ^= x0;
  x0 += k1; x1 += ks2 + 4u;
  x0 += x1; x1 = rotl32(x1,13); x1 ^= x0;
  x0 += x1; x1 = rotl32(x1,15); x1 ^= x0;
  x0 += x1; x1 = rotl32(x1,26); x1 ^= x0;
  x0 += x1; x1 = rotl32(x1, 6); x1 ^= x0;
  x0 += ks2; x1 += k0 + 5u;
  *o0 = x0; *o1 = x1;
}

// drop iff MSB(o0^o1) set (uniform<0.5 under partitionable bit-gen)
__device__ __forceinline__ uint32_t tf_dropbit(uint32_t k0, uint32_t k1, uint32_t j){
  uint32_t o0, o1;
  threefry2x32(k0, k1, 0u, j, &o0, &o1);
  return (o0 ^ o1) >> 31;
}

// single-instruction rotate: v_alignbit_b32 x,x,(32-d) == rotl(x,d)
__device__ __forceinline__ uint32_t rotl1(uint32_t x, int d){
  return __builtin_amdgcn_alignbit(x, x, (uint32_t)(32 - d));
}

// ---------------- bf16 helpers ----------------
__device__ __forceinline__ ushort f2bf(float f){
  uint32_t u = __float_as_uint(f);
  u += 0x7FFFu + ((u >> 16) & 1u);   // rne
  return (ushort)(u >> 16);
}
__device__ __forceinline__ float bf2f(ushort b){
  return __uint_as_float(((uint32_t)b) << 16);
}
// packed f32x2 -> bf16x2 (RNE), single instruction
__device__ __forceinline__ uint32_t cvt_pk_bf16(float lo, float hi){
  uint32_t r;
  asm("v_cvt_pk_bf16_f32 %0, %1, %2" : "=v"(r) : "v"(lo), "v"(hi));
  return r;
}

// 4 elements j..j+3: 4 threefry chains hand-interleaved; value-pack via
// v_cvt_pk_bf16_f32; drop via sign-mask + v_perm. {dword(e0,e1), dword(e2,e3)}.
__device__ __forceinline__ uint2 drop4(uint32_t k0, uint32_t k1, uint32_t j,
                                       float f0, float f1, float f2, float f3){
  uint32_t ks2 = k0 ^ k1 ^ 0x1BD11BDAu;
  uint32_t xa0 = k0, xa1 = (j + 0u) + k1;
  uint32_t xb0 = k0, xb1 = (j + 1u) + k1;
  uint32_t xc0 = k0, xc1 = (j + 2u) + k1;
  uint32_t xd0 = k0, xd1 = (j + 3u) + k1;
#define RR(d)                                              \
  xa0 += xa1; xa1 = rotl1(xa1, d); xa1 ^= xa0;             \
  xb0 += xb1; xb1 = rotl1(xb1, d); xb1 ^= xb0;             \
  xc0 += xc1; xc1 = rotl1(xc1, d); xc1 ^= xc0;             \
  xd0 += xd1; xd1 = rotl1(xd1, d); xd1 ^= xd0;
#define INJ(ka, kb)                                        \
  { uint32_t A = (ka), B = (kb);                           \
    xa0 += A; xa1 += B; xb0 += A; xb1 += B;                \
    xc0 += A; xc1 += B; xd0 += A; xd1 += B; }
  RR(13) RR(15) RR(26) RR(6)  INJ(k1, ks2 + 1u)
  RR(17) RR(29) RR(16) RR(24) INJ(ks2, k0 + 2u)
  RR(13) RR(15) RR(26) RR(6)  INJ(k0, k1 + 3u)
  RR(17) RR(29) RR(16) RR(24) INJ(k1, ks2 + 4u)
  RR(13) RR(15) RR(26) RR(6)  INJ(ks2, k0 + 5u)
#undef RR
#undef INJ
  uint32_t ba = xa0 ^ xa1, bb = xb0 ^ xb1, bc = xc0 ^ xc1, bd = xd0 ^ xd1;
  uint32_t sa = (uint32_t)((int32_t)ba >> 31);   // all-ones if drop
  uint32_t sb = (uint32_t)((int32_t)bb >> 31);
  uint32_t sc = (uint32_t)((int32_t)bc >> 31);
  uint32_t sd = (uint32_t)((int32_t)bd >> 31);
  uint32_t v01 = cvt_pk_bf16(f0, f1);
  uint32_t v23 = cvt_pk_bf16(f2, f3);
  uint32_t m01 = __builtin_amdgcn_perm(sb, sa, 0x07060302u);
  uint32_t m23 = __builtin_amdgcn_perm(sd, sc, 0x07060302u);
  return make_uint2(v01 & ~m01, v23 & ~m23);
}

// ---------------- K0: pack 2*W1 fragments + ck precompute (one block) --------
__global__ void k_prep(const float* __restrict__ W1, ushort* __restrict__ w1p,
                       const float* __restrict__ PI, const float* __restrict__ PREs,
                       float* __restrict__ ckg){
  int t = threadIdx.x;
  for (int u = 0; u < 32; ++u){
    int idx = u * 256 + t;            // = k*16 + c
    int k = idx >> 4, c = idx & 15;
    w1p[((k >> 3) * 16 + c) * 8 + (k & 7)] = f2bf(2.0f * W1[idx]);
  }
  if (t < 16){
    float s = logf(PI[t]);
    #pragma unroll
    for (int j = 0; j < 16; ++j) s += 0.5f * logf(PREs[t * 16 + j]);
    ckg[t] = s - 8.0f * logf(6.28318530717958647692f);
  }
}

// ---------------- K1: fused {rp scatter} + {support1 = dropout(x) @ W1} ------
// K-split x4: block = 4 waves on the SAME 16 rows, one 128-wide K-quarter each
// -> 25000 waves (24.4/SIMD). rp blocks (edge-boundary scatter) interleaved
// 2:1 hide under the hash burn.  [round-11 config: measured 130 us]
__global__ __launch_bounds__(256, 8) void k_main(
    const float* __restrict__ x, const ushort* __restrict__ w1p,
    ushort* __restrict__ s1, const int* __restrict__ rowv, int* __restrict__ rp,
    uint32_t dk0, uint32_t dk1, int N, int E, int nbG, int nbR){
  __shared__ float part[4][16][17];
  int bid = blockIdx.x;
  int m3 = bid % 3;
  if (m3 != 2){
    // ---- rp scatter block ----
    int rb = 2 * (bid / 3) + m3;
    if (rb < nbR){
      int e = rb * 256 + threadIdx.x;
      if (e <= E){
        int r0 = (e > 0) ? rowv[e - 1] : -1;
        int r1 = (e < E) ? rowv[e] : N;
        for (int r = r0 + 1; r <= r1; ++r) rp[r] = e;
      }
    }
    return;
  }
  int gb = bid / 3;
  if (gb >= nbG) return;

  int t = threadIdx.x;
  int l = t & 63, p = t >> 6;            // p = K-quarter
  int rA = l & 15, kg = l >> 4;
  int r0 = gb * 16;
  int rr = r0 + rA; if (rr > N - 1) rr = N - 1;
  const float4* xv = reinterpret_cast<const float4*>(
      x + (size_t)rr * 512 + (p * 128 + kg * 8));
  uint32_t jb = (uint32_t)rr * 512u + (uint32_t)(p * 128 + kg * 8);

  const bf16x8* bp = reinterpret_cast<const bf16x8*>(w1p);
  bf16x8 Bf[4];
  #pragma unroll
  for (int q = 0; q < 4; ++q) Bf[q] = bp[((p * 4 + q) * 4 + kg) * 16 + rA];

  float4 xa = xv[0], xb = xv[1];
  __builtin_amdgcn_sched_barrier(0);

  f32x4 acc = {0.f, 0.f, 0.f, 0.f};
  #pragma unroll
  for (int ks = 0; ks < 4; ++ks){
    float4 na, nb;
    if (ks < 3){ na = xv[(ks + 1) * 8]; nb = xv[(ks + 1) * 8 + 1]; }
    __builtin_amdgcn_sched_barrier(0);   // loads stay above, hash below
    uint32_t j0 = jb + (uint32_t)(ks * 32);
    uint2 lo = drop4(dk0, dk1, j0,      xa.x, xa.y, xa.z, xa.w);
    uint2 hi = drop4(dk0, dk1, j0 + 4u, xb.x, xb.y, xb.z, xb.w);
    i32x4 ai = {(int)lo.x, (int)lo.y, (int)hi.x, (int)hi.y};
    bf16x8 a = __builtin_bit_cast(bf16x8, ai);
    acc = __builtin_amdgcn_mfma_f32_16x16x32_bf16(a, Bf[ks], acc, 0, 0, 0);
    if (ks < 3){ xa = na; xb = nb; }
  }

  // C/D: col = lane&15, row = (lane>>4)*4 + reg -> stash partials per quarter
  #pragma unroll
  for (int i2 = 0; i2 < 4; ++i2) part[p][kg * 4 + i2][rA] = acc[i2];
  __syncthreads();
  {
    int row = t >> 4, col = t & 15;
    int n = r0 + row;
    float sum = (part[0][row][col] + part[1][row][col])
              + (part[2][row][col] + part[3][row][col]);
    if (n < N) s1[(size_t)n * 16 + col] = f2bf(sum);
  }
}

// edge-walk helper: 4-aligned vector loads with peel, 8-edge stride
__device__ __forceinline__ float edge_sum(const float* __restrict__ adj,
                                          const int* __restrict__ colv,
                                          const ushort* __restrict__ tbl_d,
                                          int e0, int e1){
  float hs = 0.f;
  int e = e0;
  int ea = (e0 + 3) & ~3; if (ea > e1) ea = e1;
  for (; e < ea; ++e) hs += adj[e] * bf2f(tbl_d[(size_t)colv[e] * 16]);
  float a0 = 0.f, a1 = 0.f, a2 = 0.f, a3 = 0.f;
  float b0 = 0.f, b1 = 0.f, b2 = 0.f, b3 = 0.f;
  for (; e + 8 <= e1; e += 8){
    float4 av = *reinterpret_cast<const float4*>(adj + e);
    int4   cv = *reinterpret_cast<const int4*>(colv + e);
    float4 aw = *reinterpret_cast<const float4*>(adj + e + 4);
    int4   cw = *reinterpret_cast<const int4*>(colv + e + 4);
    a0 += av.x * bf2f(tbl_d[(size_t)cv.x * 16]);
    a1 += av.y * bf2f(tbl_d[(size_t)cv.y * 16]);
    a2 += av.z * bf2f(tbl_d[(size_t)cv.z * 16]);
    a3 += av.w * bf2f(tbl_d[(size_t)cv.w * 16]);
    b0 += aw.x * bf2f(tbl_d[(size_t)cw.x * 16]);
    b1 += aw.y * bf2f(tbl_d[(size_t)cw.y * 16]);
    b2 += aw.z * bf2f(tbl_d[(size_t)cw.z * 16]);
    b3 += aw.w * bf2f(tbl_d[(size_t)cw.w * 16]);
  }
  if (e + 4 <= e1){
    float4 av = *reinterpret_cast<const float4*>(adj + e);
    int4   cv = *reinterpret_cast<const int4*>(colv + e);
    a0 += av.x * bf2f(tbl_d[(size_t)cv.x * 16]);
    a1 += av.y * bf2f(tbl_d[(size_t)cv.y * 16]);
    a2 += av.z * bf2f(tbl_d[(size_t)cv.z * 16]);
    a3 += av.w * bf2f(tbl_d[(size_t)cv.w * 16]);
    e += 4;
  }
  for (; e < e1; ++e) hs += adj[e] * bf2f(tbl_d[(size_t)colv[e] * 16]);
  return hs + ((a0 + b0) + (a1 + b1)) + ((a2 + b2) + (a3 + b3));
}

// ---------------- K2: h = spmm(s1); GMM-probs, relu, dropout2, @W2 -> s2(bf16) --
__global__ __launch_bounds__(256) void k_spmm1(
    const float* __restrict__ adj, const int* __restrict__ colv,
    const int* __restrict__ rp, const ushort* __restrict__ s1,
    const float* __restrict__ MUs, const float* __restrict__ PREs,
    const float* __restrict__ W2, const float* __restrict__ ckg,
    ushort* __restrict__ s2, float* __restrict__ partials,
    uint32_t dk0, uint32_t dk1, int N){
  __shared__ float muT[256], preT[256], w2s[256], ck[16];
  __shared__ float bsum;
  int t = threadIdx.x;
  {
    int j = t >> 4, k = t & 15;     // transposed: muT[j*16+k] = MUs[k][j]
    muT[t]  = MUs[k * 16 + j];
    preT[t] = PREs[k * 16 + j];
  }
  w2s[t] = W2[t];
  if (t < 16) ck[t] = ckg[t];
  if (t == 0) bsum = 0.f;
  __syncthreads();

  int i = blockIdx.x * 16 + (t >> 4);
  int d = t & 15;
  int base = t & 48;                // wave-relative 16-group base
  float h = 0.f;
  if (i < N) h = edge_sum(adj, colv, s1 + d, rp[i], rp[i + 1]);

  // GMM log-likelihood: lane's component k = d, iterate dims j
  float lc = ck[d];
  #pragma unroll
  for (int j = 0; j < 16; ++j){
    float hj = __shfl(h, base + j, 64);
    float df = hj - muT[j * 16 + d];
    lc -= 0.5f * df * df * preT[j * 16 + d];
  }
  float m = lc;
  #pragma unroll
  for (int s = 1; s < 16; s <<= 1) m = fmaxf(m, __shfl_xor(m, s, 64));
  float mrow = (d == 0 && i < N) ? m : 0.f;
  mrow += __shfl_xor(mrow, 16, 64);
  mrow += __shfl_xor(mrow, 32, 64);
  if ((t & 63) == 0) atomicAdd(&bsum, mrow);

  // relu -> dropout(dk2) -> @W2
  float v = fmaxf(h, 0.f);
  float xd2 = (i < N && !tf_dropbit(dk0, dk1, (uint32_t)i * 16u + (uint32_t)d))
              ? 2.0f * v : 0.f;
  float s2v = 0.f;
  #pragma unroll
  for (int j = 0; j < 16; ++j)
    s2v += __shfl(xd2, base + j, 64) * w2s[j * 16 + d];
  if (i < N) s2[(size_t)i * 16 + d] = f2bf(s2v);
  __syncthreads();
  if (t == 0) partials[blockIdx.x] = bsum;
}

// ---------------- K3: h2 = spmm(s2); log_softmax; block0 reduces partials ----
__global__ __launch_bounds__(256) void k_spmm2(
    const float* __restrict__ adj, const int* __restrict__ colv,
    const int* __restrict__ rp, const ushort* __restrict__ s2,
    const float* __restrict__ partials, int nparts,
    float* __restrict__ out, int N){
  int t = threadIdx.x;
  int i = blockIdx.x * 16 + (t >> 4);
  int d = t & 15;
  float h = 0.f;
  if (i < N) h = edge_sum(adj, colv, s2 + d, rp[i], rp[i + 1]);
  float m = h;
  #pragma unroll
  for (int s = 1; s < 16; s <<= 1) m = fmaxf(m, __shfl_xor(m, s, 64));
  float ex = expf(h - m);
  float ssum = ex;
  #pragma unroll
  for (int s = 1; s < 16; s <<= 1) ssum += __shfl_xor(ssum, s, 64);
  if (i < N) out[(size_t)i * 16 + d] = (h - m) - logf(ssum);

  if (blockIdx.x == 0){
    __shared__ float wsum[4];
    float s = 0.f;
    for (int q = t; q < nparts; q += 256) s += partials[q];
    #pragma unroll
    for (int sh = 1; sh < 64; sh <<= 1) s += __shfl_xor(s, sh, 64);
    if ((t & 63) == 0) wsum[t >> 6] = s;
    __syncthreads();
    if (t == 0)
      out[(size_t)N * 16] = -(wsum[0] + wsum[1] + wsum[2] + wsum[3]) / (float)N;
  }
}

extern "C" void kernel_launch(void* const* d_in, const int* in_sizes, int n_in,
                              void* d_out, int out_size, void* d_ws, size_t ws_size,
                              hipStream_t stream){
  const float* x    = (const float*)d_in[0];
  const float* W1   = (const float*)d_in[1];
  const float* W2   = (const float*)d_in[2];
  const float* adj  = (const float*)d_in[3];
  const float* PI   = (const float*)d_in[4];
  const float* MUs  = (const float*)d_in[5];
  const float* PREs = (const float*)d_in[6];
  const int*   rowv = (const int*)d_in[7];
  const int*   colv = (const int*)d_in[8];
  const int N = in_sizes[0] / 512;   // 100000
  const int E = in_sizes[3];         // 3200000
  float* out = (float*)d_out;

  // workspace layout
  char* ws = (char*)d_ws;
  float* ckg = (float*)ws;                                    // 16 floats
  int*   rp  = (int*)(ws + 256);                              // N+1 ints
  size_t rpBytes = (((size_t)(N + 1) * 4) + 255) & ~(size_t)255;
  ushort* s1 = (ushort*)(ws + 256 + rpBytes);                 // N*16 bf16
  size_t s1Bytes = (((size_t)N * 16 * 2) + 255) & ~(size_t)255;
  ushort* s2 = (ushort*)(ws + 256 + rpBytes + s1Bytes);       // N*16 bf16
  size_t s2Bytes = s1Bytes;
  float* partials = (float*)(ws + 256 + rpBytes + s1Bytes + s2Bytes);
  size_t pBytes = ((((size_t)N / 16 + 1) * 4) + 255) & ~(size_t)255;
  ushort* w1p = (ushort*)(ws + 256 + rpBytes + s1Bytes + s2Bytes + pBytes); // 16KB

  // dk1/dk2: fold-like split of key(42) = (0, 42)
  uint32_t d10, d11, d20, d21;
  threefry2x32(0u, 42u, 0u, 0u, &d10, &d11);  // dk1
  threefry2x32(0u, 42u, 0u, 1u, &d20, &d21);  // dk2

  k_prep<<<1, 256, 0, stream>>>(W1, w1p, PI, PREs, ckg);

  int nbG = N / 16;                            // 6250 gemm blocks
  int nbR = (E + 1 + 255) / 256;               // 12501 rp blocks
  // pattern: bid%3==2 -> gemm gb=bid/3 ; else rp rb=2*(bid/3)+bid%3
  int grid = 3 * nbG;                          // rb reaches 2*6249+1=12499
  while (2 * ((grid - 1) / 3) + ((grid - 1) % 3 == 2 ? 0 : (grid - 1) % 3) < nbR - 1)
    ++grid;
  k_main<<<grid, 256, 0, stream>>>(x, w1p, s1, rowv, rp, d10, d11, N, E, nbG, nbR);

  int nb2 = (N + 15) / 16;
  k_spmm1<<<nb2, 256, 0, stream>>>(adj, colv, rp, s1, MUs, PREs, W2, ckg,
                                   s2, partials, d20, d21, N);
  k_spmm2<<<nb2, 256, 0, stream>>>(adj, colv, rp, s2, partials, nb2, out, N);
}

// Round 14
// 190.386 us; speedup vs baseline: 1.7647x; 1.0280x over previous
//
#include <hip/hip_runtime.h>
#include <stdint.h>

typedef __attribute__((ext_vector_type(8))) short bf16x8;
typedef __attribute__((ext_vector_type(4))) float f32x4;
typedef __attribute__((ext_vector_type(4))) int i32x4;

// ---------------- threefry2x32 (exact JAX) ----------------
__host__ __device__ __forceinline__ uint32_t rotl32(uint32_t x, int d){
  return (x << d) | (x >> (32 - d));
}

__host__ __device__ __forceinline__ void threefry2x32(uint32_t k0, uint32_t k1,
                                                      uint32_t x0, uint32_t x1,
                                                      uint32_t* o0, uint32_t* o1){
  uint32_t ks2 = k0 ^ k1 ^ 0x1BD11BDAu;
  x0 += k0; x1 += k1;
  x0 += x1; x1 = rotl32(x1,13); x1 ^= x0;
  x0 += x1; x1 = rotl32(x1,15); x1 ^= x0;
  x0 += x1; x1 = rotl32(x1,26); x1 ^= x0;
  x0 += x1; x1 = rotl32(x1, 6); x1 ^= x0;
  x0 += k1; x1 += ks2 + 1u;
  x0 += x1; x1 = rotl32(x1,17); x1 ^= x0;
  x0 += x1; x1 = rotl32(x1,29); x1 ^= x0;
  x0 += x1; x1 = rotl32(x1,16); x1 ^= x0;
  x0 += x1; x1 = rotl32(x1,24); x1 ^= x0;
  x0 += ks2; x1 += k0 + 2u;
  x0 += x1; x1 = rotl32(x1,13); x1 ^= x0;
  x0 += x1; x1 = rotl32(x1,15); x1 ^= x0;
  x0 += x1; x1 = rotl32(x1,26); x1 ^= x0;
  x0 += x1; x1 = rotl32(x1, 6); x1 ^= x0;
  x0 += k0; x1 += k1 + 3u;
  x0 += x1; x1 = rotl32(x1,17); x1 ^= x0;
  x0 += x1; x1 = rotl32(x1,29); x1 ^= x0;
  x0 += x1; x1 = rotl32(x1,16); x1 ^= x0;
  x0 += x1; x1 = rotl32(x1,24); x1 ^= x0;
  x0 += k1; x1 += ks2 + 4u;
  x0 += x1; x1 = rotl32(x1,13); x1 ^= x0;
  x0 += x1; x1 = rotl32(x1,15); x1 ^= x0;
  x0 += x1; x1 = rotl32(x1,26); x1 ^= x0;
  x0 += x1; x1 = rotl32(x1, 6); x1 ^= x0;
  x0 += ks2; x1 += k0 + 5u;
  *o0 = x0; *o1 = x1;
}

// drop iff MSB(o0^o1) set (uniform<0.5 under partitionable bit-gen)
__device__ __forceinline__ uint32_t tf_dropbit(uint32_t k0, uint32_t k1, uint32_t j){
  uint32_t o0, o1;
  threefry2x32(k0, k1, 0u, j, &o0, &o1);
  return (o0 ^ o1) >> 31;
}

// single-instruction rotate: v_alignbit_b32 x,x,(32-d) == rotl(x,d)
__device__ __forceinline__ uint32_t rotl1(uint32_t x, int d){
  return __builtin_amdgcn_alignbit(x, x, (uint32_t)(32 - d));
}

// ---------------- bf16 helpers ----------------
__device__ __forceinline__ ushort f2bf(float f){
  uint32_t u = __float_as_uint(f);
  u += 0x7FFFu + ((u >> 16) & 1u);   // rne
  return (ushort)(u >> 16);
}
__device__ __forceinline__ float bf2f(ushort b){
  return __uint_as_float(((uint32_t)b) << 16);
}
// packed f32x2 -> bf16x2 (RNE), single instruction
__device__ __forceinline__ uint32_t cvt_pk_bf16(float lo, float hi){
  uint32_t r;
  asm("v_cvt_pk_bf16_f32 %0, %1, %2" : "=v"(r) : "v"(lo), "v"(hi));
  return r;
}

// 4 elements j..j+3: 4 threefry chains hand-interleaved; value-pack via
// v_cvt_pk_bf16_f32; drop via sign-mask + v_perm. {dword(e0,e1), dword(e2,e3)}.
__device__ __forceinline__ uint2 drop4(uint32_t k0, uint32_t k1, uint32_t j,
                                       float f0, float f1, float f2, float f3){
  uint32_t ks2 = k0 ^ k1 ^ 0x1BD11BDAu;
  uint32_t xa0 = k0, xa1 = (j + 0u) + k1;
  uint32_t xb0 = k0, xb1 = (j + 1u) + k1;
  uint32_t xc0 = k0, xc1 = (j + 2u) + k1;
  uint32_t xd0 = k0, xd1 = (j + 3u) + k1;
#define RR(d)                                              \
  xa0 += xa1; xa1 = rotl1(xa1, d); xa1 ^= xa0;             \
  xb0 += xb1; xb1 = rotl1(xb1, d); xb1 ^= xb0;             \
  xc0 += xc1; xc1 = rotl1(xc1, d); xc1 ^= xc0;             \
  xd0 += xd1; xd1 = rotl1(xd1, d); xd1 ^= xd0;
#define INJ(ka, kb)                                        \
  { uint32_t A = (ka), B = (kb);                           \
    xa0 += A; xa1 += B; xb0 += A; xb1 += B;                \
    xc0 += A; xc1 += B; xd0 += A; xd1 += B; }
  RR(13) RR(15) RR(26) RR(6)  INJ(k1, ks2 + 1u)
  RR(17) RR(29) RR(16) RR(24) INJ(ks2, k0 + 2u)
  RR(13) RR(15) RR(26) RR(6)  INJ(k0, k1 + 3u)
  RR(17) RR(29) RR(16) RR(24) INJ(k1, ks2 + 4u)
  RR(13) RR(15) RR(26) RR(6)  INJ(ks2, k0 + 5u)
#undef RR
#undef INJ
  uint32_t ba = xa0 ^ xa1, bb = xb0 ^ xb1, bc = xc0 ^ xc1, bd = xd0 ^ xd1;
  uint32_t sa = (uint32_t)((int32_t)ba >> 31);   // all-ones if drop
  uint32_t sb = (uint32_t)((int32_t)bb >> 31);
  uint32_t sc = (uint32_t)((int32_t)bc >> 31);
  uint32_t sd = (uint32_t)((int32_t)bd >> 31);
  uint32_t v01 = cvt_pk_bf16(f0, f1);
  uint32_t v23 = cvt_pk_bf16(f2, f3);
  uint32_t m01 = __builtin_amdgcn_perm(sb, sa, 0x07060302u);
  uint32_t m23 = __builtin_amdgcn_perm(sd, sc, 0x07060302u);
  return make_uint2(v01 & ~m01, v23 & ~m23);
}

// ---------------- K0: pack 2*W1 fragments + ck precompute (one block) --------
__global__ void k_prep(const float* __restrict__ W1, ushort* __restrict__ w1p,
                       const float* __restrict__ PI, const float* __restrict__ PREs,
                       float* __restrict__ ckg){
  int t = threadIdx.x;
  for (int u = 0; u < 32; ++u){
    int idx = u * 256 + t;            // = k*16 + c
    int k = idx >> 4, c = idx & 15;
    w1p[((k >> 3) * 16 + c) * 8 + (k & 7)] = f2bf(2.0f * W1[idx]);
  }
  if (t < 16){
    float s = logf(PI[t]);
    #pragma unroll
    for (int j = 0; j < 16; ++j) s += 0.5f * logf(PREs[t * 16 + j]);
    ckg[t] = s - 8.0f * logf(6.28318530717958647692f);
  }
}

// ---------------- K1: fused {rp scatter x4} + {support1 = dropout(x) @ W1} ---
// Gemm: K-split x4 (round-11 config, measured 130 us). rp scatter now handles
// FOUR boundaries/thread via one int4 load -> 12.5K rp waves (was 50K), less
// wave-slot pollution of the hash burn. Interleave 1 rp : 2 gemm.
__global__ __launch_bounds__(256, 8) void k_main(
    const float* __restrict__ x, const ushort* __restrict__ w1p,
    ushort* __restrict__ s1, const int* __restrict__ rowv, int* __restrict__ rp,
    uint32_t dk0, uint32_t dk1, int N, int E, int nbG, int nbR){
  __shared__ float part[4][16][17];
  int bid = blockIdx.x;
  if (bid % 3 == 0){
    // ---- rp scatter block: 4 boundaries per thread ----
    int rb = bid / 3;
    if (rb < nbR){
      int e4 = (rb * 256 + threadIdx.x) * 4;
      if (e4 + 3 < E){
        int4 v = *reinterpret_cast<const int4*>(rowv + e4);
        int rm1 = (e4 > 0) ? rowv[e4 - 1] : -1;
        for (int r = rm1 + 1; r <= v.x; ++r) rp[r] = e4;
        for (int r = v.x + 1; r <= v.y; ++r) rp[r] = e4 + 1;
        for (int r = v.y + 1; r <= v.z; ++r) rp[r] = e4 + 2;
        for (int r = v.z + 1; r <= v.w; ++r) rp[r] = e4 + 3;
      } else if (e4 <= E){
        int elim = (e4 + 3 < E) ? (e4 + 3) : E;
        for (int e = e4; e <= elim; ++e){
          int r0 = (e > 0) ? rowv[e - 1] : -1;
          int r1 = (e < E) ? rowv[e] : N;
          for (int r = r0 + 1; r <= r1; ++r) rp[r] = e;
        }
      }
    }
    return;
  }
  int gb = bid - bid / 3 - 1;
  if (gb >= nbG) return;

  int t = threadIdx.x;
  int l = t & 63, p = t >> 6;            // p = K-quarter
  int rA = l & 15, kg = l >> 4;
  int r0 = gb * 16;
  int rr = r0 + rA; if (rr > N - 1) rr = N - 1;
  const float4* xv = reinterpret_cast<const float4*>(
      x + (size_t)rr * 512 + (p * 128 + kg * 8));
  uint32_t jb = (uint32_t)rr * 512u + (uint32_t)(p * 128 + kg * 8);

  const bf16x8* bp = reinterpret_cast<const bf16x8*>(w1p);
  bf16x8 Bf[4];
  #pragma unroll
  for (int q = 0; q < 4; ++q) Bf[q] = bp[((p * 4 + q) * 4 + kg) * 16 + rA];

  float4 xa = xv[0], xb = xv[1];
  __builtin_amdgcn_sched_barrier(0);

  f32x4 acc = {0.f, 0.f, 0.f, 0.f};
  #pragma unroll
  for (int ks = 0; ks < 4; ++ks){
    float4 na, nb;
    if (ks < 3){ na = xv[(ks + 1) * 8]; nb = xv[(ks + 1) * 8 + 1]; }
    __builtin_amdgcn_sched_barrier(0);   // loads stay above, hash below
    uint32_t j0 = jb + (uint32_t)(ks * 32);
    uint2 lo = drop4(dk0, dk1, j0,      xa.x, xa.y, xa.z, xa.w);
    uint2 hi = drop4(dk0, dk1, j0 + 4u, xb.x, xb.y, xb.z, xb.w);
    i32x4 ai = {(int)lo.x, (int)lo.y, (int)hi.x, (int)hi.y};
    bf16x8 a = __builtin_bit_cast(bf16x8, ai);
    acc = __builtin_amdgcn_mfma_f32_16x16x32_bf16(a, Bf[ks], acc, 0, 0, 0);
    if (ks < 3){ xa = na; xb = nb; }
  }

  // C/D: col = lane&15, row = (lane>>4)*4 + reg -> stash partials per quarter
  #pragma unroll
  for (int i2 = 0; i2 < 4; ++i2) part[p][kg * 4 + i2][rA] = acc[i2];
  __syncthreads();
  {
    int row = t >> 4, col = t & 15;
    int n = r0 + row;
    float sum = (part[0][row][col] + part[1][row][col])
              + (part[2][row][col] + part[3][row][col]);
    if (n < N) s1[(size_t)n * 16 + col] = f2bf(sum);
  }
}

// edge-walk helper: 4-aligned vector loads with peel, 8-edge stride
__device__ __forceinline__ float edge_sum(const float* __restrict__ adj,
                                          const int* __restrict__ colv,
                                          const ushort* __restrict__ tbl_d,
                                          int e0, int e1){
  float hs = 0.f;
  int e = e0;
  int ea = (e0 + 3) & ~3; if (ea > e1) ea = e1;
  for (; e < ea; ++e) hs += adj[e] * bf2f(tbl_d[(size_t)colv[e] * 16]);
  float a0 = 0.f, a1 = 0.f, a2 = 0.f, a3 = 0.f;
  float b0 = 0.f, b1 = 0.f, b2 = 0.f, b3 = 0.f;
  for (; e + 8 <= e1; e += 8){
    float4 av = *reinterpret_cast<const float4*>(adj + e);
    int4   cv = *reinterpret_cast<const int4*>(colv + e);
    float4 aw = *reinterpret_cast<const float4*>(adj + e + 4);
    int4   cw = *reinterpret_cast<const int4*>(colv + e + 4);
    a0 += av.x * bf2f(tbl_d[(size_t)cv.x * 16]);
    a1 += av.y * bf2f(tbl_d[(size_t)cv.y * 16]);
    a2 += av.z * bf2f(tbl_d[(size_t)cv.z * 16]);
    a3 += av.w * bf2f(tbl_d[(size_t)cv.w * 16]);
    b0 += aw.x * bf2f(tbl_d[(size_t)cw.x * 16]);
    b1 += aw.y * bf2f(tbl_d[(size_t)cw.y * 16]);
    b2 += aw.z * bf2f(tbl_d[(size_t)cw.z * 16]);
    b3 += aw.w * bf2f(tbl_d[(size_t)cw.w * 16]);
  }
  if (e + 4 <= e1){
    float4 av = *reinterpret_cast<const float4*>(adj + e);
    int4   cv = *reinterpret_cast<const int4*>(colv + e);
    a0 += av.x * bf2f(tbl_d[(size_t)cv.x * 16]);
    a1 += av.y * bf2f(tbl_d[(size_t)cv.y * 16]);
    a2 += av.z * bf2f(tbl_d[(size_t)cv.z * 16]);
    a3 += av.w * bf2f(tbl_d[(size_t)cv.w * 16]);
    e += 4;
  }
  for (; e < e1; ++e) hs += adj[e] * bf2f(tbl_d[(size_t)colv[e] * 16]);
  return hs + ((a0 + b0) + (a1 + b1)) + ((a2 + b2) + (a3 + b3));
}

// ---------------- K2: h = spmm(s1); GMM-probs, relu, dropout2, @W2 -> s2(bf16) --
__global__ __launch_bounds__(256) void k_spmm1(
    const float* __restrict__ adj, const int* __restrict__ colv,
    const int* __restrict__ rp, const ushort* __restrict__ s1,
    const float* __restrict__ MUs, const float* __restrict__ PREs,
    const float* __restrict__ W2, const float* __restrict__ ckg,
    ushort* __restrict__ s2, float* __restrict__ partials,
    uint32_t dk0, uint32_t dk1, int N){
  __shared__ float muT[256], preT[256], w2s[256], ck[16];
  __shared__ float bsum;
  int t = threadIdx.x;
  {
    int j = t >> 4, k = t & 15;     // transposed: muT[j*16+k] = MUs[k][j]
    muT[t]  = MUs[k * 16 + j];
    preT[t] = PREs[k * 16 + j];
  }
  w2s[t] = W2[t];
  if (t < 16) ck[t] = ckg[t];
  if (t == 0) bsum = 0.f;
  __syncthreads();

  int i = blockIdx.x * 16 + (t >> 4);
  int d = t & 15;
  int base = t & 48;                // wave-relative 16-group base
  float h = 0.f;
  if (i < N) h = edge_sum(adj, colv, s1 + d, rp[i], rp[i + 1]);

  // GMM log-likelihood: lane's component k = d, iterate dims j
  float lc = ck[d];
  #pragma unroll
  for (int j = 0; j < 16; ++j){
    float hj = __shfl(h, base + j, 64);
    float df = hj - muT[j * 16 + d];
    lc -= 0.5f * df * df * preT[j * 16 + d];
  }
  float m = lc;
  #pragma unroll
  for (int s = 1; s < 16; s <<= 1) m = fmaxf(m, __shfl_xor(m, s, 64));
  float mrow = (d == 0 && i < N) ? m : 0.f;
  mrow += __shfl_xor(mrow, 16, 64);
  mrow += __shfl_xor(mrow, 32, 64);
  if ((t & 63) == 0) atomicAdd(&bsum, mrow);

  // relu -> dropout(dk2) -> @W2
  float v = fmaxf(h, 0.f);
  float xd2 = (i < N && !tf_dropbit(dk0, dk1, (uint32_t)i * 16u + (uint32_t)d))
              ? 2.0f * v : 0.f;
  float s2v = 0.f;
  #pragma unroll
  for (int j = 0; j < 16; ++j)
    s2v += __shfl(xd2, base + j, 64) * w2s[j * 16 + d];
  if (i < N) s2[(size_t)i * 16 + d] = f2bf(s2v);
  __syncthreads();
  if (t == 0) partials[blockIdx.x] = bsum;
}

// ---------------- K3: h2 = spmm(s2); log_softmax; block0 reduces partials ----
__global__ __launch_bounds__(256) void k_spmm2(
    const float* __restrict__ adj, const int* __restrict__ colv,
    const int* __restrict__ rp, const ushort* __restrict__ s2,
    const float* __restrict__ partials, int nparts,
    float* __restrict__ out, int N){
  int t = threadIdx.x;
  int i = blockIdx.x * 16 + (t >> 4);
  int d = t & 15;
  float h = 0.f;
  if (i < N) h = edge_sum(adj, colv, s2 + d, rp[i], rp[i + 1]);
  float m = h;
  #pragma unroll
  for (int s = 1; s < 16; s <<= 1) m = fmaxf(m, __shfl_xor(m, s, 64));
  float ex = expf(h - m);
  float ssum = ex;
  #pragma unroll
  for (int s = 1; s < 16; s <<= 1) ssum += __shfl_xor(ssum, s, 64);
  if (i < N) out[(size_t)i * 16 + d] = (h - m) - logf(ssum);

  if (blockIdx.x == 0){
    __shared__ float wsum[4];
    float s = 0.f;
    for (int q = t; q < nparts; q += 256) s += partials[q];
    #pragma unroll
    for (int sh = 1; sh < 64; sh <<= 1) s += __shfl_xor(s, sh, 64);
    if ((t & 63) == 0) wsum[t >> 6] = s;
    __syncthreads();
    if (t == 0)
      out[(size_t)N * 16] = -(wsum[0] + wsum[1] + wsum[2] + wsum[3]) / (float)N;
  }
}

extern "C" void kernel_launch(void* const* d_in, const int* in_sizes, int n_in,
                              void* d_out, int out_size, void* d_ws, size_t ws_size,
                              hipStream_t stream){
  const float* x    = (const float*)d_in[0];
  const float* W1   = (const float*)d_in[1];
  const float* W2   = (const float*)d_in[2];
  const float* adj  = (const float*)d_in[3];
  const float* PI   = (const float*)d_in[4];
  const float* MUs  = (const float*)d_in[5];
  const float* PREs = (const float*)d_in[6];
  const int*   rowv = (const int*)d_in[7];
  const int*   colv = (const int*)d_in[8];
  const int N = in_sizes[0] / 512;   // 100000
  const int E = in_sizes[3];         // 3200000
  float* out = (float*)d_out;

  // workspace layout
  char* ws = (char*)d_ws;
  float* ckg = (float*)ws;                                    // 16 floats
  int*   rp  = (int*)(ws + 256);                              // N+1 ints
  size_t rpBytes = (((size_t)(N + 1) * 4) + 255) & ~(size_t)255;
  ushort* s1 = (ushort*)(ws + 256 + rpBytes);                 // N*16 bf16
  size_t s1Bytes = (((size_t)N * 16 * 2) + 255) & ~(size_t)255;
  ushort* s2 = (ushort*)(ws + 256 + rpBytes + s1Bytes);       // N*16 bf16
  size_t s2Bytes = s1Bytes;
  float* partials = (float*)(ws + 256 + rpBytes + s1Bytes + s2Bytes);
  size_t pBytes = ((((size_t)N / 16 + 1) * 4) + 255) & ~(size_t)255;
  ushort* w1p = (ushort*)(ws + 256 + rpBytes + s1Bytes + s2Bytes + pBytes); // 16KB

  // dk1/dk2: fold-like split of key(42) = (0, 42)
  uint32_t d10, d11, d20, d21;
  threefry2x32(0u, 42u, 0u, 0u, &d10, &d11);  // dk1
  threefry2x32(0u, 42u, 0u, 1u, &d20, &d21);  // dk2

  k_prep<<<1, 256, 0, stream>>>(W1, w1p, PI, PREs, ckg);

  int nbG = N / 16;                            // 6250 gemm blocks
  int nbR = (E / 4 + 1 + 255) / 256;           // 3126 rp blocks (4 bnd/thread)
  // pattern: bid%3==0 -> rp rb=bid/3 ; else gemm gb=bid-bid/3-1
  int grid = 3 * nbG / 2 + 2;                  // gemm needs gb up to 6249
  while ((grid - 1) - (grid - 1) / 3 - 1 < nbG - 1) ++grid;
  while ((grid - 1) / 3 < nbR - 1) ++grid;     // rp needs rb up to 3125
  k_main<<<grid, 256, 0, stream>>>(x, w1p, s1, rowv, rp, d10, d11, N, E, nbG, nbR);

  int nb2 = (N + 15) / 16;
  k_spmm1<<<nb2, 256, 0, stream>>>(adj, colv, rp, s1, MUs, PREs, W2, ckg,
                                   s2, partials, d20, d21, N);
  k_spmm2<<<nb2, 256, 0, stream>>>(adj, colv, rp, s2, partials, nb2, out, N);
}